// Round 13
// baseline (1141.786 us; speedup 1.0000x reference)
//
#include <hip/hip_runtime.h>
#include <hip/hip_bf16.h>
#include <math.h>

typedef unsigned short u16;
typedef unsigned int u32;
typedef __attribute__((ext_vector_type(8))) short short8;   // 8 bf16 (4 VGPRs)
typedef __attribute__((ext_vector_type(4))) float f32x4;    // MFMA acc

#define NB 8
#define SL 512
#define DM 256
#define DI 512
#define NTOK (NB*SL)           // 4096 tokens
#define EPSF 1e-5f

// per-direction buffer strides
#define XZS (NTOK*2*DI)        // xz: (B,L,1024)
#define XCS (NTOK*DI)          // xc / y: (B,L,512)
#define XDS (NTOK*48)          // xdbl: (B,L,48)

// chunked scan: 16 chunks x 32 steps; fused kernel = 256 blocks (1/CU, co-resident)
#define NC 16
#define CL 32
#define NBLK (NC*NB*2)         // 256

// ---------------- workspace (device globals) ----
__device__ __align__(16) float g_feat[NTOK*DM];
__device__ __align__(16) float g_xz  [2*XZS];
__device__ __align__(16) float g_xc  [2*XCS];
__device__ __align__(16) float g_xdbl[2*XDS];
__device__ __align__(16) float g_outf[NTOK*DM];
__device__ __align__(16) float g_outb[NTOK*DM];
__device__ __align__(16) float g_sumA[2*NB*NC*16*DI];
__device__ __align__(16) float g_sumS[2*NB*NC*16*DI];
__device__ __align__(16) float g_ent [2*NB*NC*16*DI];
__device__ __align__(16) float g_pool[NB*8*256];
__device__ u32 g_bar[8];       // 4 layers x 2 barriers
// bf16 hi/lo split buffers
__device__ __align__(16) u16 g_fh[NTOK*DM];
__device__ __align__(16) u16 g_fl[NTOK*DM];
__device__ __align__(16) u16 g_yh[2*XCS];
__device__ __align__(16) u16 g_yl[2*XCS];
__device__ __align__(16) u16 g_iwh[2*4*1024*DM];
__device__ __align__(16) u16 g_iwl[2*4*1024*DM];
__device__ __align__(16) u16 g_owh[2*4*DM*DI];
__device__ __align__(16) u16 g_owl[2*4*DM*DI];

// ---------------- helpers ----------------
__device__ __forceinline__ float siluf(float v){ return v/(1.0f+__expf(-v)); }
__device__ __forceinline__ float softplusf(float v){ return fmaxf(v,0.0f)+log1pf(__expf(-fabsf(v))); }
__device__ __forceinline__ float b2f(u16 u){ union { u32 i; float f; } v; v.i=((u32)u)<<16; return v.f; }
__device__ __forceinline__ u16 f2b(float f){ union { float f; u32 i; } v; v.f=f; u32 r=v.i+0x7fffu+((v.i>>16)&1u); return (u16)(r>>16); }
__device__ __forceinline__ void bsplit(float v, u16* h, u16* l){
  u16 hb=f2b(v); *h=hb; *l=f2b(v-b2f(hb));
}

__device__ __forceinline__ void meanvar256(float v, float &mu, float &var, float* red){
  float s=v, q=v*v;
  #pragma unroll
  for (int off=32; off>0; off>>=1){ s+=__shfl_down(s,off); q+=__shfl_down(q,off); }
  int lane=threadIdx.x&63, w=threadIdx.x>>6;
  if (lane==0){ red[w]=s; red[4+w]=q; }
  __syncthreads();
  float st=red[0]+red[1]+red[2]+red[3];
  float qt=red[4]+red[5]+red[6]+red[7];
  mu=st*(1.0f/256.0f);
  var=qt*(1.0f/256.0f)-mu*mu;
  __syncthreads();
}

// device-scope grid barrier; ctr used once per kernel launch (zeroed host-side)
__device__ __forceinline__ void gridbar(u32* ctr){
  __syncthreads();
  if (threadIdx.x==0){
    __threadfence();                 // release prior global writes
    atomicAdd(ctr, 1u);              // device-scope arrive
    while (__hip_atomic_load(ctr, __ATOMIC_ACQUIRE, __HIP_MEMORY_SCOPE_AGENT) < (u32)NBLK)
      __builtin_amdgcn_s_sleep(8);
    __threadfence();                 // acquire others' writes
  }
  __syncthreads();
}

// ---------------- fp32 -> bf16 hi/lo weight split, both dirs ----------------
__global__ __launch_bounds__(256) void k_cvt2(const float* __restrict__ s0, const float* __restrict__ s1,
  u16* __restrict__ h, u16* __restrict__ l, int n)
{
  int dir=blockIdx.y;
  const float* s = dir?s1:s0;
  int i=blockIdx.x*256+threadIdx.x;
  if (i<n) bsplit(s[i], &h[(size_t)dir*n+i], &l[(size_t)dir*n+i]);
}

// ---------------- tokenize: 4 tokens/block (1024 blocks), LDS-staged Wfus -------
#define TT 4
__global__ __launch_bounds__(256) void k_tokenize(
  const float* __restrict__ x, const float* __restrict__ embp, const float* __restrict__ embf,
  const float* __restrict__ embd, const float* __restrict__ Wlen, const float* __restrict__ blen,
  const float* __restrict__ Wiat, const float* __restrict__ biat, const float* __restrict__ Wfus,
  const float* __restrict__ bfus, const float* __restrict__ g, const float* __restrict__ bt,
  float* __restrict__ feat, u16* __restrict__ fh, u16* __restrict__ fl)
{
  int bl0=blockIdx.x*TT, t=threadIdx.x;
  __shared__ float cat[TT][136];
  __shared__ float sW[256*9];
  __shared__ float red[8];
  for (int f=t; f<TT*136; f+=256){
    int tok=f/136, j=f-tok*136, bl=bl0+tok;
    float cv;
    if      (j<32 ){ int p=min(255,max(0,(int)x[bl*5+0])); cv=embp[p*32+j]; }
    else if (j<64 ){ cv=fmaf(Wlen[j-32],x[bl*5+1],blen[j-32]); }
    else if (j<96 ){ int fl2=min(63,max(0,(int)x[bl*5+2])); cv=embf[fl2*32+(j-64)]; }
    else if (j<128){ cv=fmaf(Wiat[j-96],x[bl*5+3],biat[j-96]); }
    else           { int dd=min(1,max(0,(int)x[bl*5+4])); cv=embd[dd*8+(j-128)]; }
    cat[tok][j]=cv;
  }
  float acc[TT];
  float bf=bfus[t];
  #pragma unroll
  for (int tok=0;tok<TT;tok++) acc[tok]=bf;
  for (int kk0=0; kk0<136; kk0+=8){
    __syncthreads();
    for (int f=t; f<2048; f+=256){
      int tr=f>>3, j=f&7;
      sW[tr*9+j]=Wfus[tr*136+kk0+j];
    }
    __syncthreads();
    #pragma unroll
    for (int j=0;j<8;j++){
      float w=sW[t*9+j];
      #pragma unroll
      for (int tok=0;tok<TT;tok++) acc[tok]=fmaf(w,cat[tok][kk0+j],acc[tok]);
    }
  }
  __syncthreads();
  float gv=g[t], bv=bt[t];
  #pragma unroll
  for (int tok=0;tok<TT;tok++){
    float mu,var; meanvar256(acc[tok],mu,var,red);
    float o=fmaf((acc[tok]-mu)*rsqrtf(var+EPSF),gv,bv);
    size_t idx=(size_t)(bl0+tok)*256+t;
    feat[idx]=o; bsplit(o,&fh[idx],&fl[idx]);
  }
}

// ---------------- MFMA GEMM (bf16 hi/lo split, fp32 acc) -----------------------
__global__ __launch_bounds__(256) void k_gemmM(
  const u16* __restrict__ Ah0, const u16* __restrict__ Al0,
  const u16* __restrict__ Ah1, const u16* __restrict__ Al1, int lda,
  const u16* __restrict__ Bh0, const u16* __restrict__ Bl0,
  const u16* __restrict__ Bh1, const u16* __restrict__ Bl1, int K,
  float* __restrict__ C0, float* __restrict__ C1, int ldc)
{
  const u16* Ah = blockIdx.z?Ah1:Ah0; const u16* Al = blockIdx.z?Al1:Al0;
  const u16* Bh = blockIdx.z?Bh1:Bh0; const u16* Bl = blockIdx.z?Bl1:Bl0;
  float* C = blockIdx.z?C1:C0;
  __shared__ __align__(16) u16 sAh[64*40], sAl[64*40], sBh[64*40], sBl[64*40];
  int tid=threadIdx.x;
  int bm=blockIdx.y*64, bn=blockIdx.x*64;
  int wave=tid>>6, lane=tid&63;
  int quad=lane>>4, l16=lane&15;
  int wm=(wave&1)*32, wn=(wave>>1)*32;
  f32x4 acc[2][2]={};
  int r=tid>>2, sg=(tid&3)*8;
  for (int k0=0;k0<K;k0+=32){
    *(uint4*)&sAh[r*40+sg] = *(const uint4*)(Ah + (size_t)(bm+r)*lda + k0 + sg);
    *(uint4*)&sAl[r*40+sg] = *(const uint4*)(Al + (size_t)(bm+r)*lda + k0 + sg);
    *(uint4*)&sBh[r*40+sg] = *(const uint4*)(Bh + (size_t)(bn+r)*K   + k0 + sg);
    *(uint4*)&sBl[r*40+sg] = *(const uint4*)(Bl + (size_t)(bn+r)*K   + k0 + sg);
    __syncthreads();
    short8 ah[2], al[2], bh[2], bl[2];
    #pragma unroll
    for (int t=0;t<2;t++){
      ah[t]=*(const short8*)&sAh[(wm+t*16+l16)*40+quad*8];
      al[t]=*(const short8*)&sAl[(wm+t*16+l16)*40+quad*8];
      bh[t]=*(const short8*)&sBh[(wn+t*16+l16)*40+quad*8];
      bl[t]=*(const short8*)&sBl[(wn+t*16+l16)*40+quad*8];
    }
    #pragma unroll
    for (int mt=0;mt<2;mt++)
      #pragma unroll
      for (int nt=0;nt<2;nt++){
        acc[mt][nt]=__builtin_amdgcn_mfma_f32_16x16x32_bf16(ah[mt],bh[nt],acc[mt][nt],0,0,0);
        acc[mt][nt]=__builtin_amdgcn_mfma_f32_16x16x32_bf16(al[mt],bh[nt],acc[mt][nt],0,0,0);
        acc[mt][nt]=__builtin_amdgcn_mfma_f32_16x16x32_bf16(ah[mt],bl[nt],acc[mt][nt],0,0,0);
      }
    __syncthreads();
  }
  #pragma unroll
  for (int mt=0;mt<2;mt++)
    #pragma unroll
    for (int nt=0;nt<2;nt++)
      #pragma unroll
      for (int reg=0;reg<4;reg++){
        int m=bm+wm+mt*16+quad*4+reg;
        int n=bn+wn+nt*16+l16;
        C[(size_t)m*ldc+n]=acc[mt][nt][reg];
      }
}

// ---------------- x_proj split-K GEMM (fp32, atomics) ----------------
__global__ __launch_bounds__(256) void k_gemmSK(
  const float* __restrict__ A0, const float* __restrict__ A1, int lda,
  const float* __restrict__ B0, const float* __restrict__ B1, int K,
  float* __restrict__ C0, float* __restrict__ C1, int ldc)
{
  int dir=blockIdx.z;
  const float* A = dir ? A1 : A0;
  const float* Bw= dir ? B1 : B0;
  float*       C = dir ? C1 : C0;
  int ks=blockIdx.x;
  int bm=blockIdx.y*64;
  __shared__ float As[16][68];
  __shared__ float Bs[16][52];
  int tid=threadIdx.x;
  int tx=tid%16, ty=tid/16;
  int tm0=ty*4, tn0=tx*3;
  float acc[4][3]={};
  int kbeg=ks*128, kend=kbeg+128;
  for (int k0=kbeg;k0<kend;k0+=16){
    { int m=tid>>2, kq=(tid&3)<<2;
      float4 v = *(const float4*)(A + (size_t)(bm+m)*lda + k0 + kq);
      As[kq+0][m]=v.x; As[kq+1][m]=v.y; As[kq+2][m]=v.z; As[kq+3][m]=v.w; }
    if (tid<192){ int n=tid>>2, kq=(tid&3)<<2;
      float4 v = *(const float4*)(Bw + (size_t)n*K + k0 + kq);
      Bs[kq+0][n]=v.x; Bs[kq+1][n]=v.y; Bs[kq+2][n]=v.z; Bs[kq+3][n]=v.w; }
    __syncthreads();
    #pragma unroll
    for (int k=0;k<16;k++){
      float4 a = *(const float4*)&As[k][tm0];
      float b0=Bs[k][tn0], b1=Bs[k][tn0+1], b2=Bs[k][tn0+2];
      acc[0][0]=fmaf(a.x,b0,acc[0][0]); acc[0][1]=fmaf(a.x,b1,acc[0][1]); acc[0][2]=fmaf(a.x,b2,acc[0][2]);
      acc[1][0]=fmaf(a.y,b0,acc[1][0]); acc[1][1]=fmaf(a.y,b1,acc[1][1]); acc[1][2]=fmaf(a.y,b2,acc[1][2]);
      acc[2][0]=fmaf(a.z,b0,acc[2][0]); acc[2][1]=fmaf(a.z,b1,acc[2][1]); acc[2][2]=fmaf(a.z,b2,acc[2][2]);
      acc[3][0]=fmaf(a.w,b0,acc[3][0]); acc[3][1]=fmaf(a.w,b1,acc[3][1]); acc[3][2]=fmaf(a.w,b2,acc[3][2]);
    }
    __syncthreads();
  }
  #pragma unroll
  for (int i=0;i<4;i++)
    #pragma unroll
    for (int j=0;j<3;j++)
      atomicAdd(&C[(size_t)(bm+tm0+i)*ldc + tn0+j], acc[i][j]);
}

// ---------------- depthwise causal conv4 + SiLU, both dirs ----------------
__global__ __launch_bounds__(256) void k_conv2(const float* __restrict__ xz,
  const float* __restrict__ cw0, const float* __restrict__ cw1,
  const float* __restrict__ cb0, const float* __restrict__ cb1,
  float* __restrict__ xc)
{
  int dir=blockIdx.y;
  const float* xzp = xz + (size_t)dir*XZS;
  float*       xcp = (float*)xc + (size_t)dir*XCS;
  const float* cw = dir?cw1:cw0;
  const float* cb = dir?cb1:cb0;
  int idx=blockIdx.x*256+threadIdx.x;
  int d=idx&511; int bl=idx>>9; int l=bl&511; int b=bl>>9;
  float acc=cb[d];
  #pragma unroll
  for (int k=0;k<4;k++){
    int lk = dir ? (l+3-k) : (l-3+k);
    if (lk>=0 && lk<512)
      acc=fmaf(cw[d*4+k], xzp[(((size_t)(b*512+lk))<<10)+d], acc);
  }
  xcp[idx]=siluf(acc);
}

// ---------------- fused chunked selective scan (A + prefix + B, one kernel) -----
// 256 blocks (1/CU, co-resident), 512 threads = d. Grid barriers between phases.
// Phase A: local scan, cache dl[CL], xv[CL] in regs; write chunk summaries.
// Phase P: 131072 prefix chains (one per thread) over NC chunk summaries -> ent.
// Phase B: reload entry h, re-scan with cached dl/xv + LDS-resident B/C.
__global__ __launch_bounds__(512) void k_scanF(
  const float* __restrict__ xc, const float* __restrict__ xdbl,
  const float* __restrict__ xz,
  const float* __restrict__ ALf, const float* __restrict__ ALb,
  const float* __restrict__ Wdtf, const float* __restrict__ Wdtb,
  const float* __restrict__ bdtf, const float* __restrict__ bdtb,
  const float* __restrict__ DPf, const float* __restrict__ DPb,
  float* __restrict__ sumA, float* __restrict__ sumS, float* __restrict__ ent,
  u16* __restrict__ yh, u16* __restrict__ yl, u32* __restrict__ bar)
{
  int c=blockIdx.x, b=blockIdx.y, dir=blockIdx.z;
  int d=threadIdx.x;
  const float* AL  = dir?ALb:ALf;
  const float* Wdt = dir?Wdtb:Wdtf;
  const float* bdt = dir?bdtb:bdtf;
  const float* DP  = dir?DPb:DPf;
  const float* xc_p = xc  + (size_t)dir*XCS;
  const float* xd_p = xdbl+ (size_t)dir*XDS;
  const float* xz_p = xz  + (size_t)dir*XZS;
  u16* yh_p = yh + (size_t)dir*XCS;
  u16* yl_p = yl + (size_t)dir*XCS;

  __shared__ __align__(16) float sBC[CL][48];
  for (int f=d; f<CL*48; f+=512){
    int ll=f/48, j=f-ll*48;
    int l = dir ? (511-(c*CL+ll)) : (c*CL+ll);
    sBC[ll][j] = xd_p[((size_t)b*512+l)*48+j];
  }
  __syncthreads();

  float A[16], W[16];
  const float4* ALv = (const float4*)(AL + d*16);
  const float4* Wv  = (const float4*)(Wdt + d*16);
  #pragma unroll
  for (int i=0;i<4;i++){
    float4 v = ALv[i];
    A[4*i+0]=-__expf(v.x); A[4*i+1]=-__expf(v.y);
    A[4*i+2]=-__expf(v.z); A[4*i+3]=-__expf(v.w);
    float4 w = Wv[i];
    W[4*i+0]=w.x; W[4*i+1]=w.y; W[4*i+2]=w.z; W[4*i+3]=w.w;
  }
  float bd = bdt[d];

  // ---- phase A: local scan from h=0; cache dl/xv ----
  float dl[CL], xv[CL];
  float h[16], ap[16];
  #pragma unroll
  for (int s=0;s<16;s++){ h[s]=0.f; ap[s]=1.f; }
  // step base index (l walks ±1 from chunk start)
  int l0 = dir ? (511-c*CL) : (c*CL);
  int lstep = dir ? -1 : 1;
  #pragma unroll 4
  for (int ll=0; ll<CL; ll++){
    size_t bl=(size_t)b*512 + (l0 + ll*lstep);
    float dt=bd;
    #pragma unroll
    for (int r2=0;r2<16;r2++) dt=fmaf(sBC[ll][r2],W[r2],dt);
    float dlv = softplusf(dt);
    float xvv = xc_p[bl*512+d];
    dl[ll]=dlv; xv[ll]=xvv;
    float du = dlv*xvv;
    #pragma unroll
    for (int s=0;s<16;s++){
      float a = __expf(dlv*A[s]);
      h[s]=fmaf(a,h[s],du*sBC[ll][16+s]);
      ap[s]*=a;
    }
  }
  size_t sbase = ((((size_t)dir*NB+b)*NC+c)*16)*DI + d;
  #pragma unroll
  for (int s=0;s<16;s++){
    sumA[sbase + (size_t)s*DI] = ap[s];
    sumS[sbase + (size_t)s*DI] = h[s];
  }

  gridbar(bar+0);

  // ---- phase P: one prefix chain per thread ----
  {
    int gid = (((blockIdx.z*NB)+blockIdx.y)*NC+blockIdx.x)*512 + d;
    int d2=gid&511, s2=(gid>>9)&15, b2=(gid>>13)&7, dir2=(gid>>16)&1;
    size_t stride_c = (size_t)16*DI;
    size_t base = ((size_t)(dir2*NB+b2)*NC)*16*DI + (size_t)s2*DI + d2;
    float hp=0.f;
    #pragma unroll
    for (int c2=0;c2<NC;c2++){
      size_t off = base + (size_t)c2*stride_c;
      ent[off] = hp;
      hp = fmaf(sumA[off], hp, sumS[off]);
    }
  }

  gridbar(bar+1);

  // ---- phase B: re-scan with entry state; emit gated y (bf16 hi/lo) ----
  #pragma unroll
  for (int s=0;s<16;s++) h[s]=ent[sbase + (size_t)s*DI];
  float Dv = DP[d];
  #pragma unroll 4
  for (int ll=0; ll<CL; ll++){
    size_t bl=(size_t)b*512 + (l0 + ll*lstep);
    float dlv=dl[ll], xvv=xv[ll];
    float zv = xz_p[(bl<<10)+512+d];
    float du = dlv*xvv;
    float y=0.f;
    #pragma unroll
    for (int s=0;s<16;s++){
      float a = __expf(dlv*A[s]);
      h[s]=fmaf(a,h[s],du*sBC[ll][16+s]);
      y=fmaf(h[s],sBC[ll][32+s],y);
    }
    y=fmaf(xvv,Dv,y);
    float gv = y*siluf(zv);
    bsplit(gv, &yh_p[bl*512+d], &yl_p[bl*512+d]);
  }
}

// ---------------- residual + LayerNorm (+ bf16 hi/lo emit) ----------------
__global__ __launch_bounds__(256) void k_resln(const float* __restrict__ of, const float* __restrict__ ob,
  float* __restrict__ feat, const float* __restrict__ g, const float* __restrict__ bb,
  u16* __restrict__ fh, u16* __restrict__ fl)
{
  int i=blockIdx.x*256+threadIdx.x;
  __shared__ float red[8];
  float v=of[i]+ob[i]+feat[i];
  float mu,var; meanvar256(v,mu,var,red);
  float o=fmaf((v-mu)*rsqrtf(var+EPSF),g[threadIdx.x],bb[threadIdx.x]);
  feat[i]=o; bsplit(o,&fh[i],&fl[i]);
}

// ---------------- two-stage mean-pool + MLP head ----------------
__global__ __launch_bounds__(256) void k_pool(const float* __restrict__ feat, float* __restrict__ pool)
{
  int seg=blockIdx.x, b=blockIdx.y, t=threadIdx.x;
  float acc=0.f;
  for (int l=seg*64;l<seg*64+64;l++) acc+=feat[((size_t)b*512+l)*256+t];
  pool[((size_t)b*8+seg)*256+t]=acc;
}

__global__ __launch_bounds__(256) void k_head(const float* __restrict__ pool, const float* __restrict__ W1,
  const float* __restrict__ bb1, const float* __restrict__ W2, const float* __restrict__ bb2,
  float* __restrict__ out)
{
  int b=blockIdx.x, t=threadIdx.x;
  __shared__ float sp[256], sh[256];
  float acc=0.0f;
  #pragma unroll
  for (int seg=0;seg<8;seg++) acc+=pool[((size_t)b*8+seg)*256+t];
  sp[t]=acc*(1.0f/512.0f);
  __syncthreads();
  float a=bb1[t];
  for (int k=0;k<256;k++) a=fmaf(sp[k],W1[t*256+k],a);
  sh[t]=fmaxf(a,0.0f);
  __syncthreads();
  float o=bb2[t];
  for (int k=0;k<256;k++) o=fmaf(sh[k],W2[t*256+k],o);
  out[b*256+t]=o;
}

// ---------------- launch ----------------
extern "C" void kernel_launch(void* const* d_in, const int* in_sizes, int n_in,
                              void* d_out, int out_size, void* d_ws, size_t ws_size,
                              hipStream_t stream)
{
  (void)in_sizes; (void)n_in; (void)d_ws; (void)ws_size; (void)out_size;

  const float* X   =(const float*)d_in[0];
  const float* EMBP=(const float*)d_in[1];
  const float* EMBF=(const float*)d_in[2];
  const float* EMBD=(const float*)d_in[3];
  const float* WLEN=(const float*)d_in[4];
  const float* BLEN=(const float*)d_in[5];
  const float* WIAT=(const float*)d_in[6];
  const float* BIAT=(const float*)d_in[7];
  const float* WFUS=(const float*)d_in[8];
  const float* BFUS=(const float*)d_in[9];
  const float* GTOK=(const float*)d_in[10];
  const float* BTOK=(const float*)d_in[11];
  const float* GN  =(const float*)d_in[12];
  const float* BNb =(const float*)d_in[13];
  const float* WH1 =(const float*)d_in[14];
  const float* BH1 =(const float*)d_in[15];
  const float* WH2 =(const float*)d_in[16];
  const float* BH2 =(const float*)d_in[17];
  const float* INW[2]={(const float*)d_in[18],(const float*)d_in[27]};
  const float* CW [2]={(const float*)d_in[19],(const float*)d_in[28]};
  const float* CB [2]={(const float*)d_in[20],(const float*)d_in[29]};
  const float* XPW[2]={(const float*)d_in[21],(const float*)d_in[30]};
  const float* DTW[2]={(const float*)d_in[22],(const float*)d_in[31]};
  const float* DTB[2]={(const float*)d_in[23],(const float*)d_in[32]};
  const float* AL [2]={(const float*)d_in[24],(const float*)d_in[33]};
  const float* DP [2]={(const float*)d_in[25],(const float*)d_in[34]};
  const float* OW [2]={(const float*)d_in[26],(const float*)d_in[35]};

  float *feat,*xz,*xc,*xdbl,*outf,*outb,*sumA,*sumS,*ent,*pool;
  u16 *fh,*fl,*yh,*yl,*iwh,*iwl,*owh,*owl; u32 *bar;
  hipGetSymbolAddress((void**)&feat, HIP_SYMBOL(g_feat));
  hipGetSymbolAddress((void**)&xz,   HIP_SYMBOL(g_xz));
  hipGetSymbolAddress((void**)&xc,   HIP_SYMBOL(g_xc));
  hipGetSymbolAddress((void**)&xdbl, HIP_SYMBOL(g_xdbl));
  hipGetSymbolAddress((void**)&outf, HIP_SYMBOL(g_outf));
  hipGetSymbolAddress((void**)&outb, HIP_SYMBOL(g_outb));
  hipGetSymbolAddress((void**)&sumA, HIP_SYMBOL(g_sumA));
  hipGetSymbolAddress((void**)&sumS, HIP_SYMBOL(g_sumS));
  hipGetSymbolAddress((void**)&ent,  HIP_SYMBOL(g_ent));
  hipGetSymbolAddress((void**)&pool, HIP_SYMBOL(g_pool));
  hipGetSymbolAddress((void**)&bar,  HIP_SYMBOL(g_bar));
  hipGetSymbolAddress((void**)&fh,   HIP_SYMBOL(g_fh));
  hipGetSymbolAddress((void**)&fl,   HIP_SYMBOL(g_fl));
  hipGetSymbolAddress((void**)&yh,   HIP_SYMBOL(g_yh));
  hipGetSymbolAddress((void**)&yl,   HIP_SYMBOL(g_yl));
  hipGetSymbolAddress((void**)&iwh,  HIP_SYMBOL(g_iwh));
  hipGetSymbolAddress((void**)&iwl,  HIP_SYMBOL(g_iwl));
  hipGetSymbolAddress((void**)&owh,  HIP_SYMBOL(g_owh));
  hipGetSymbolAddress((void**)&owl,  HIP_SYMBOL(g_owl));

  // zero the 8 barrier counters (one per layer x phase) for this call
  hipMemsetAsync(bar, 0, 8*sizeof(u32), stream);

  // split weights to bf16 hi/lo (both dirs per dispatch)
  const int NIW = 4*1024*DM, NOW = 4*DM*DI;
  k_cvt2<<<dim3((NIW+255)/256,2),256,0,stream>>>(INW[0],INW[1], iwh, iwl, NIW);
  k_cvt2<<<dim3((NOW+255)/256,2),256,0,stream>>>(OW[0], OW[1],  owh, owl, NOW);

  k_tokenize<<<NTOK/TT,256,0,stream>>>(X,EMBP,EMBF,EMBD,WLEN,BLEN,WIAT,BIAT,WFUS,BFUS,GTOK,BTOK,feat,fh,fl);
  for (int layer=0; layer<4; layer++){
    size_t iwoff = (size_t)layer*1024*DM;
    size_t owoff = (size_t)layer*DM*DI;
    // in_proj (MFMA): (4096x1024) = feat(4096x256) @ Wp^T
    k_gemmM<<<dim3(1024/64,4096/64,2),256,0,stream>>>(
      fh,fl,fh,fl,256,
      iwh+iwoff, iwl+iwoff, iwh+NIW+iwoff, iwl+NIW+iwoff, 256,
      xz, xz+XZS, 1024);
    // conv + silu, both dirs
    k_conv2<<<dim3(NTOK*DI/256,2),256,0,stream>>>(xz,
      CW[0]+(size_t)layer*512*4, CW[1]+(size_t)layer*512*4,
      CB[0]+(size_t)layer*512,   CB[1]+(size_t)layer*512, xc);
    // x_proj split-K (fp32): (4096x48) = xc(4096x512) @ Wx^T
    hipMemsetAsync(xdbl, 0, sizeof(float)*2*XDS, stream);
    k_gemmSK<<<dim3(4,64,2),256,0,stream>>>(
      xc, xc+XCS, 512,
      XPW[0]+(size_t)layer*48*512, XPW[1]+(size_t)layer*48*512, 512,
      xdbl, xdbl+XDS, 48);
    // fused chunked scan (A + prefix + B), 256 co-resident blocks
    k_scanF<<<dim3(NC,NB,2),512,0,stream>>>(xc,xdbl,xz,
      AL[0]+(size_t)layer*512*16, AL[1]+(size_t)layer*512*16,
      DTW[0]+(size_t)layer*512*16, DTW[1]+(size_t)layer*512*16,
      DTB[0]+(size_t)layer*512,    DTB[1]+(size_t)layer*512,
      DP[0]+(size_t)layer*512,     DP[1]+(size_t)layer*512,
      sumA,sumS,ent, yh,yl, bar+layer*2);
    // out_proj (MFMA): (4096x256) = y(4096x512) @ Wo^T
    k_gemmM<<<dim3(256/64,4096/64,2),256,0,stream>>>(
      yh,yl, yh+XCS,yl+XCS, 512,
      owh+owoff, owl+owoff, owh+NOW+owoff, owl+NOW+owoff, 512,
      outf, outb, 256);
    k_resln<<<NTOK,256,0,stream>>>(outf,outb,feat,GN,BNb,fh,fl);
  }
  k_pool<<<dim3(8,NB),256,0,stream>>>(feat,pool);
  k_head<<<NB,256,0,stream>>>(pool,WH1,BH1,WH2,BH2,(float*)d_out);
}

// Round 14
// 855.708 us; speedup vs baseline: 1.3343x; 1.3343x over previous
//
#include <hip/hip_runtime.h>
#include <hip/hip_bf16.h>
#include <math.h>

typedef unsigned short u16;
typedef unsigned int u32;
typedef __attribute__((ext_vector_type(8))) short short8;   // 8 bf16 (4 VGPRs)
typedef __attribute__((ext_vector_type(4))) float f32x4;    // MFMA acc

#define NB 8
#define SL 512
#define DM 256
#define DI 512
#define NTOK (NB*SL)           // 4096 tokens
#define EPSF 1e-5f

// per-direction buffer strides
#define XZS (NTOK*2*DI)        // xz: (B,L,1024)
#define XCS (NTOK*DI)          // xc / y / dlt: (B,L,512)
#define XDS (NTOK*48)          // xdbl: (B,L,48)

// chunked scan: 16 chunks x 32 steps (988-proven trio config)
#define NC 16
#define CL 32

// ---------------- workspace (device globals) ----
__device__ __align__(16) float g_feat[NTOK*DM];
__device__ __align__(16) float g_xz  [2*XZS];
__device__ __align__(16) float g_xc  [2*XCS];
__device__ __align__(16) float g_xdbl4[4*2*XDS];     // x_proj partials [ks][dir]
__device__ __align__(16) float g_dlt [2*XCS];        // delta (scanA -> scanB)
__device__ __align__(16) float g_outf[NTOK*DM];
__device__ __align__(16) float g_outb[NTOK*DM];
__device__ __align__(16) float g_sumA[2*NB*NC*16*DI];
__device__ __align__(16) float g_sumS[2*NB*NC*16*DI];
__device__ __align__(16) float g_ent [2*NB*NC*16*DI];
__device__ __align__(16) float g_pool[NB*8*256];
// bf16 hi/lo split buffers
__device__ __align__(16) u16 g_fh[NTOK*DM];
__device__ __align__(16) u16 g_fl[NTOK*DM];
__device__ __align__(16) u16 g_yh[2*XCS];
__device__ __align__(16) u16 g_yl[2*XCS];
__device__ __align__(16) u16 g_iwh[2*4*1024*DM];
__device__ __align__(16) u16 g_iwl[2*4*1024*DM];
__device__ __align__(16) u16 g_owh[2*4*DM*DI];
__device__ __align__(16) u16 g_owl[2*4*DM*DI];

// ---------------- helpers ----------------
__device__ __forceinline__ float siluf(float v){ return v/(1.0f+__expf(-v)); }
__device__ __forceinline__ float softplusf(float v){ return fmaxf(v,0.0f)+log1pf(__expf(-fabsf(v))); }
__device__ __forceinline__ float b2f(u16 u){ union { u32 i; float f; } v; v.i=((u32)u)<<16; return v.f; }
__device__ __forceinline__ u16 f2b(float f){ union { float f; u32 i; } v; v.f=f; u32 r=v.i+0x7fffu+((v.i>>16)&1u); return (u16)(r>>16); }
__device__ __forceinline__ void bsplit(float v, u16* h, u16* l){
  u16 hb=f2b(v); *h=hb; *l=f2b(v-b2f(hb));
}

__device__ __forceinline__ void meanvar256(float v, float &mu, float &var, float* red){
  float s=v, q=v*v;
  #pragma unroll
  for (int off=32; off>0; off>>=1){ s+=__shfl_down(s,off); q+=__shfl_down(q,off); }
  int lane=threadIdx.x&63, w=threadIdx.x>>6;
  if (lane==0){ red[w]=s; red[4+w]=q; }
  __syncthreads();
  float st=red[0]+red[1]+red[2]+red[3];
  float qt=red[4]+red[5]+red[6]+red[7];
  mu=st*(1.0f/256.0f);
  var=qt*(1.0f/256.0f)-mu*mu;
  __syncthreads();
}

// ---------------- fp32 -> bf16 hi/lo weight split, both dirs ----------------
__global__ __launch_bounds__(256) void k_cvt2(const float* __restrict__ s0, const float* __restrict__ s1,
  u16* __restrict__ h, u16* __restrict__ l, int n)
{
  int dir=blockIdx.y;
  const float* s = dir?s1:s0;
  int i=blockIdx.x*256+threadIdx.x;
  if (i<n) bsplit(s[i], &h[(size_t)dir*n+i], &l[(size_t)dir*n+i]);
}

// ---------------- tokenize: 4 tokens/block (1024 blocks), LDS-staged Wfus -------
#define TT 4
__global__ __launch_bounds__(256) void k_tokenize(
  const float* __restrict__ x, const float* __restrict__ embp, const float* __restrict__ embf,
  const float* __restrict__ embd, const float* __restrict__ Wlen, const float* __restrict__ blen,
  const float* __restrict__ Wiat, const float* __restrict__ biat, const float* __restrict__ Wfus,
  const float* __restrict__ bfus, const float* __restrict__ g, const float* __restrict__ bt,
  float* __restrict__ feat, u16* __restrict__ fh, u16* __restrict__ fl)
{
  int bl0=blockIdx.x*TT, t=threadIdx.x;
  __shared__ float cat[TT][136];
  __shared__ float sW[256*9];
  __shared__ float red[8];
  for (int f=t; f<TT*136; f+=256){
    int tok=f/136, j=f-tok*136, bl=bl0+tok;
    float cv;
    if      (j<32 ){ int p=min(255,max(0,(int)x[bl*5+0])); cv=embp[p*32+j]; }
    else if (j<64 ){ cv=fmaf(Wlen[j-32],x[bl*5+1],blen[j-32]); }
    else if (j<96 ){ int fl2=min(63,max(0,(int)x[bl*5+2])); cv=embf[fl2*32+(j-64)]; }
    else if (j<128){ cv=fmaf(Wiat[j-96],x[bl*5+3],biat[j-96]); }
    else           { int dd=min(1,max(0,(int)x[bl*5+4])); cv=embd[dd*8+(j-128)]; }
    cat[tok][j]=cv;
  }
  float acc[TT];
  float bf=bfus[t];
  #pragma unroll
  for (int tok=0;tok<TT;tok++) acc[tok]=bf;
  for (int kk0=0; kk0<136; kk0+=8){
    __syncthreads();
    for (int f=t; f<2048; f+=256){
      int tr=f>>3, j=f&7;
      sW[tr*9+j]=Wfus[tr*136+kk0+j];
    }
    __syncthreads();
    #pragma unroll
    for (int j=0;j<8;j++){
      float w=sW[t*9+j];
      #pragma unroll
      for (int tok=0;tok<TT;tok++) acc[tok]=fmaf(w,cat[tok][kk0+j],acc[tok]);
    }
  }
  __syncthreads();
  float gv=g[t], bv=bt[t];
  #pragma unroll
  for (int tok=0;tok<TT;tok++){
    float mu,var; meanvar256(acc[tok],mu,var,red);
    float o=fmaf((acc[tok]-mu)*rsqrtf(var+EPSF),gv,bv);
    size_t idx=(size_t)(bl0+tok)*256+t;
    feat[idx]=o; bsplit(o,&fh[idx],&fl[idx]);
  }
}

// ---------------- MFMA GEMM (bf16 hi/lo split, fp32 acc) -----------------------
__global__ __launch_bounds__(256) void k_gemmM(
  const u16* __restrict__ Ah0, const u16* __restrict__ Al0,
  const u16* __restrict__ Ah1, const u16* __restrict__ Al1, int lda,
  const u16* __restrict__ Bh0, const u16* __restrict__ Bl0,
  const u16* __restrict__ Bh1, const u16* __restrict__ Bl1, int K,
  float* __restrict__ C0, float* __restrict__ C1, int ldc)
{
  const u16* Ah = blockIdx.z?Ah1:Ah0; const u16* Al = blockIdx.z?Al1:Al0;
  const u16* Bh = blockIdx.z?Bh1:Bh0; const u16* Bl = blockIdx.z?Bl1:Bl0;
  float* C = blockIdx.z?C1:C0;
  __shared__ __align__(16) u16 sAh[64*40], sAl[64*40], sBh[64*40], sBl[64*40];
  int tid=threadIdx.x;
  int bm=blockIdx.y*64, bn=blockIdx.x*64;
  int wave=tid>>6, lane=tid&63;
  int quad=lane>>4, l16=lane&15;
  int wm=(wave&1)*32, wn=(wave>>1)*32;
  f32x4 acc[2][2]={};
  int r=tid>>2, sg=(tid&3)*8;
  for (int k0=0;k0<K;k0+=32){
    *(uint4*)&sAh[r*40+sg] = *(const uint4*)(Ah + (size_t)(bm+r)*lda + k0 + sg);
    *(uint4*)&sAl[r*40+sg] = *(const uint4*)(Al + (size_t)(bm+r)*lda + k0 + sg);
    *(uint4*)&sBh[r*40+sg] = *(const uint4*)(Bh + (size_t)(bn+r)*K   + k0 + sg);
    *(uint4*)&sBl[r*40+sg] = *(const uint4*)(Bl + (size_t)(bn+r)*K   + k0 + sg);
    __syncthreads();
    short8 ah[2], al[2], bh[2], bl[2];
    #pragma unroll
    for (int t=0;t<2;t++){
      ah[t]=*(const short8*)&sAh[(wm+t*16+l16)*40+quad*8];
      al[t]=*(const short8*)&sAl[(wm+t*16+l16)*40+quad*8];
      bh[t]=*(const short8*)&sBh[(wn+t*16+l16)*40+quad*8];
      bl[t]=*(const short8*)&sBl[(wn+t*16+l16)*40+quad*8];
    }
    #pragma unroll
    for (int mt=0;mt<2;mt++)
      #pragma unroll
      for (int nt=0;nt<2;nt++){
        acc[mt][nt]=__builtin_amdgcn_mfma_f32_16x16x32_bf16(ah[mt],bh[nt],acc[mt][nt],0,0,0);
        acc[mt][nt]=__builtin_amdgcn_mfma_f32_16x16x32_bf16(al[mt],bh[nt],acc[mt][nt],0,0,0);
        acc[mt][nt]=__builtin_amdgcn_mfma_f32_16x16x32_bf16(ah[mt],bl[nt],acc[mt][nt],0,0,0);
      }
    __syncthreads();
  }
  #pragma unroll
  for (int mt=0;mt<2;mt++)
    #pragma unroll
    for (int nt=0;nt<2;nt++)
      #pragma unroll
      for (int reg=0;reg<4;reg++){
        int m=bm+wm+mt*16+quad*4+reg;
        int n=bn+wn+nt*16+l16;
        C[(size_t)m*ldc+n]=acc[mt][nt][reg];
      }
}

// ---------------- x_proj split-K GEMM -> 4 partial buffers (no atomics) ---------
__global__ __launch_bounds__(256) void k_gemmSK(
  const float* __restrict__ A0, const float* __restrict__ A1, int lda,
  const float* __restrict__ B0, const float* __restrict__ B1, int K,
  float* __restrict__ Cp)
{
  int dir=blockIdx.z;
  const float* A = dir ? A1 : A0;
  const float* Bw= dir ? B1 : B0;
  int ks=blockIdx.x;
  float* C = Cp + ((size_t)ks*2 + dir)*XDS;
  int bm=blockIdx.y*64;
  __shared__ float As[16][68];
  __shared__ float Bs[16][52];
  int tid=threadIdx.x;
  int tx=tid%16, ty=tid/16;
  int tm0=ty*4, tn0=tx*3;
  float acc[4][3]={};
  int kbeg=ks*128, kend=kbeg+128;
  for (int k0=kbeg;k0<kend;k0+=16){
    { int m=tid>>2, kq=(tid&3)<<2;
      float4 v = *(const float4*)(A + (size_t)(bm+m)*lda + k0 + kq);
      As[kq+0][m]=v.x; As[kq+1][m]=v.y; As[kq+2][m]=v.z; As[kq+3][m]=v.w; }
    if (tid<192){ int n=tid>>2, kq=(tid&3)<<2;
      float4 v = *(const float4*)(Bw + (size_t)n*K + k0 + kq);
      Bs[kq+0][n]=v.x; Bs[kq+1][n]=v.y; Bs[kq+2][n]=v.z; Bs[kq+3][n]=v.w; }
    __syncthreads();
    #pragma unroll
    for (int k=0;k<16;k++){
      float4 a = *(const float4*)&As[k][tm0];
      float b0=Bs[k][tn0], b1=Bs[k][tn0+1], b2=Bs[k][tn0+2];
      acc[0][0]=fmaf(a.x,b0,acc[0][0]); acc[0][1]=fmaf(a.x,b1,acc[0][1]); acc[0][2]=fmaf(a.x,b2,acc[0][2]);
      acc[1][0]=fmaf(a.y,b0,acc[1][0]); acc[1][1]=fmaf(a.y,b1,acc[1][1]); acc[1][2]=fmaf(a.y,b2,acc[1][2]);
      acc[2][0]=fmaf(a.z,b0,acc[2][0]); acc[2][1]=fmaf(a.z,b1,acc[2][1]); acc[2][2]=fmaf(a.z,b2,acc[2][2]);
      acc[3][0]=fmaf(a.w,b0,acc[3][0]); acc[3][1]=fmaf(a.w,b1,acc[3][1]); acc[3][2]=fmaf(a.w,b2,acc[3][2]);
    }
    __syncthreads();
  }
  #pragma unroll
  for (int i=0;i<4;i++)
    #pragma unroll
    for (int j=0;j<3;j++)
      C[(size_t)(bm+tm0+i)*48 + tn0+j] = acc[i][j];
}

// ---------------- depthwise causal conv4 + SiLU, both dirs ----------------
__global__ __launch_bounds__(256) void k_conv2(const float* __restrict__ xz,
  const float* __restrict__ cw0, const float* __restrict__ cw1,
  const float* __restrict__ cb0, const float* __restrict__ cb1,
  float* __restrict__ xc)
{
  int dir=blockIdx.y;
  const float* xzp = xz + (size_t)dir*XZS;
  float*       xcp = (float*)xc + (size_t)dir*XCS;
  const float* cw = dir?cw1:cw0;
  const float* cb = dir?cb1:cb0;
  int idx=blockIdx.x*256+threadIdx.x;
  int d=idx&511; int bl=idx>>9; int l=bl&511; int b=bl>>9;
  float acc=cb[d];
  #pragma unroll
  for (int k=0;k<4;k++){
    int lk = dir ? (l+3-k) : (l-3+k);
    if (lk>=0 && lk<512)
      acc=fmaf(cw[d*4+k], xzp[(((size_t)(b*512+lk))<<10)+d], acc);
  }
  xcp[idx]=siluf(acc);
}

// ---------------- chunked selective scan trio ----------------------------------
// scanA: stage dt|B (sum of 4 x_proj partials) -> local scan; STORE delta to dlt.
__global__ __launch_bounds__(512) void k_scanA(
  const float* __restrict__ xc, const float* __restrict__ xd4,
  const float* __restrict__ ALf, const float* __restrict__ ALb,
  const float* __restrict__ Wdtf, const float* __restrict__ Wdtb,
  const float* __restrict__ bdtf, const float* __restrict__ bdtb,
  float* __restrict__ dlt, float* __restrict__ sumA, float* __restrict__ sumS)
{
  int c=blockIdx.x, b=blockIdx.y, dir=blockIdx.z;
  int d=threadIdx.x;
  const float* AL  = dir?ALb:ALf;
  const float* Wdt = dir?Wdtb:Wdtf;
  const float* bdt = dir?bdtb:bdtf;
  const float* xc_p = xc + (size_t)dir*XCS;
  const float* p0 = xd4 + (size_t)dir*XDS;
  float* dl_p = dlt + (size_t)dir*XCS;
  __shared__ __align__(16) float sBC[CL][32];   // [0..15]=dt, [16..31]=B
  for (int f=d; f<CL*32; f+=512){
    int ll=f>>5, j=f&31;
    int l = dir ? (511-(c*CL+ll)) : (c*CL+ll);
    size_t idx=((size_t)b*512+l)*48+j;
    sBC[ll][j] = (p0[idx]+p0[idx+2*XDS])+(p0[idx+4*XDS]+p0[idx+6*XDS]);
  }
  __syncthreads();
  float A[16], W[16];
  const float4* ALv = (const float4*)(AL + d*16);
  const float4* Wv  = (const float4*)(Wdt + d*16);
  #pragma unroll
  for (int i=0;i<4;i++){
    float4 v = ALv[i];
    A[4*i+0]=-__expf(v.x); A[4*i+1]=-__expf(v.y);
    A[4*i+2]=-__expf(v.z); A[4*i+3]=-__expf(v.w);
    float4 w = Wv[i];
    W[4*i+0]=w.x; W[4*i+1]=w.y; W[4*i+2]=w.z; W[4*i+3]=w.w;
  }
  float bd = bdt[d];
  float h[16], ap[16];
  #pragma unroll
  for (int s=0;s<16;s++){ h[s]=0.f; ap[s]=1.f; }
  int l0 = dir ? (511-c*CL) : (c*CL);
  int lstep = dir ? -1 : 1;
  for (int ll=0; ll<CL; ll++){
    size_t bl=(size_t)b*512 + (l0 + ll*lstep);
    float dt=bd;
    #pragma unroll
    for (int r2=0;r2<16;r2++) dt=fmaf(sBC[ll][r2],W[r2],dt);
    float dlv = softplusf(dt);
    dl_p[bl*512+d]=dlv;
    float xv = xc_p[bl*512+d];
    float du = dlv*xv;
    #pragma unroll
    for (int s=0;s<16;s++){
      float a = __expf(dlv*A[s]);
      h[s]=fmaf(a,h[s],du*sBC[ll][16+s]);
      ap[s]*=a;
    }
  }
  size_t base = ((((size_t)dir*NB+b)*NC+c)*16)*DI + d;
  #pragma unroll
  for (int s=0;s<16;s++){
    sumA[base + (size_t)s*DI] = ap[s];
    sumS[base + (size_t)s*DI] = h[s];
  }
}

__global__ __launch_bounds__(256) void k_scanP(
  const float* __restrict__ sumA, const float* __restrict__ sumS,
  float* __restrict__ ent)
{
  int s=blockIdx.x>>1;
  int d=((blockIdx.x&1)<<8)+threadIdx.x;
  int b=blockIdx.y, dir=blockIdx.z;
  size_t stride_c = (size_t)16*DI;
  size_t base = (((size_t)dir*NB+b)*NC*16 + s)*DI + d;
  float h=0.f;
  #pragma unroll
  for (int c=0;c<NC;c++){
    size_t off = base + (size_t)c*stride_c;
    ent[off] = h;
    h = fmaf(sumA[off], h, sumS[off]);
  }
}

// scanB: loads precomputed delta; stages only B|C; emits gated y (bf16 hi/lo).
__global__ __launch_bounds__(512) void k_scanB(
  const float* __restrict__ xc, const float* __restrict__ xd4,
  const float* __restrict__ xz, const float* __restrict__ dlt,
  const float* __restrict__ ALf, const float* __restrict__ ALb,
  const float* __restrict__ DPf, const float* __restrict__ DPb,
  const float* __restrict__ ent, u16* __restrict__ yh, u16* __restrict__ yl)
{
  int c=blockIdx.x, b=blockIdx.y, dir=blockIdx.z;
  int d=threadIdx.x;
  const float* AL  = dir?ALb:ALf;
  const float* DP  = dir?DPb:DPf;
  const float* xc_p = xc + (size_t)dir*XCS;
  const float* p0 = xd4 + (size_t)dir*XDS;
  const float* xz_p = xz + (size_t)dir*XZS;
  const float* dl_p = dlt + (size_t)dir*XCS;
  u16* yh_p = yh + (size_t)dir*XCS;
  u16* yl_p = yl + (size_t)dir*XCS;
  __shared__ __align__(16) float sBC[CL][32];   // [0..15]=B, [16..31]=C
  for (int f=d; f<CL*32; f+=512){
    int ll=f>>5, j=f&31;
    int l = dir ? (511-(c*CL+ll)) : (c*CL+ll);
    size_t idx=((size_t)b*512+l)*48+16+j;
    sBC[ll][j] = (p0[idx]+p0[idx+2*XDS])+(p0[idx+4*XDS]+p0[idx+6*XDS]);
  }
  __syncthreads();
  float A[16];
  const float4* ALv = (const float4*)(AL + d*16);
  #pragma unroll
  for (int i=0;i<4;i++){
    float4 v = ALv[i];
    A[4*i+0]=-__expf(v.x); A[4*i+1]=-__expf(v.y);
    A[4*i+2]=-__expf(v.z); A[4*i+3]=-__expf(v.w);
  }
  float h[16];
  size_t base = ((((size_t)dir*NB+b)*NC+c)*16)*DI + d;
  #pragma unroll
  for (int s=0;s<16;s++) h[s]=ent[base + (size_t)s*DI];
  float Dv = DP[d];
  int l0 = dir ? (511-c*CL) : (c*CL);
  int lstep = dir ? -1 : 1;
  for (int ll=0; ll<CL; ll++){
    size_t bl=(size_t)b*512 + (l0 + ll*lstep);
    float dlv = dl_p[bl*512+d];
    float xv  = xc_p[bl*512+d];
    float zv  = xz_p[(bl<<10)+512+d];
    float du = dlv*xv;
    float y=0.f;
    #pragma unroll
    for (int s=0;s<16;s++){
      float a = __expf(dlv*A[s]);
      h[s]=fmaf(a,h[s],du*sBC[ll][s]);
      y=fmaf(h[s],sBC[ll][16+s],y);
    }
    y=fmaf(xv,Dv,y);
    float gv = y*siluf(zv);
    bsplit(gv, &yh_p[bl*512+d], &yl_p[bl*512+d]);
  }
}

// ---------------- residual + LayerNorm (+ bf16 hi/lo emit) ----------------
__global__ __launch_bounds__(256) void k_resln(const float* __restrict__ of, const float* __restrict__ ob,
  float* __restrict__ feat, const float* __restrict__ g, const float* __restrict__ bb,
  u16* __restrict__ fh, u16* __restrict__ fl)
{
  int i=blockIdx.x*256+threadIdx.x;
  __shared__ float red[8];
  float v=of[i]+ob[i]+feat[i];
  float mu,var; meanvar256(v,mu,var,red);
  float o=fmaf((v-mu)*rsqrtf(var+EPSF),g[threadIdx.x],bb[threadIdx.x]);
  feat[i]=o; bsplit(o,&fh[i],&fl[i]);
}

// ---------------- two-stage mean-pool + MLP head ----------------
__global__ __launch_bounds__(256) void k_pool(const float* __restrict__ feat, float* __restrict__ pool)
{
  int seg=blockIdx.x, b=blockIdx.y, t=threadIdx.x;
  float acc=0.f;
  for (int l=seg*64;l<seg*64+64;l++) acc+=feat[((size_t)b*512+l)*256+t];
  pool[((size_t)b*8+seg)*256+t]=acc;
}

__global__ __launch_bounds__(256) void k_head(const float* __restrict__ pool, const float* __restrict__ W1,
  const float* __restrict__ bb1, const float* __restrict__ W2, const float* __restrict__ bb2,
  float* __restrict__ out)
{
  int b=blockIdx.x, t=threadIdx.x;
  __shared__ float sp[256], sh[256];
  float acc=0.0f;
  #pragma unroll
  for (int seg=0;seg<8;seg++) acc+=pool[((size_t)b*8+seg)*256+t];
  sp[t]=acc*(1.0f/512.0f);
  __syncthreads();
  float a=bb1[t];
  for (int k=0;k<256;k++) a=fmaf(sp[k],W1[t*256+k],a);
  sh[t]=fmaxf(a,0.0f);
  __syncthreads();
  float o=bb2[t];
  for (int k=0;k<256;k++) o=fmaf(sh[k],W2[t*256+k],o);
  out[b*256+t]=o;
}

// ---------------- launch ----------------
extern "C" void kernel_launch(void* const* d_in, const int* in_sizes, int n_in,
                              void* d_out, int out_size, void* d_ws, size_t ws_size,
                              hipStream_t stream)
{
  (void)in_sizes; (void)n_in; (void)d_ws; (void)ws_size; (void)out_size;

  const float* X   =(const float*)d_in[0];
  const float* EMBP=(const float*)d_in[1];
  const float* EMBF=(const float*)d_in[2];
  const float* EMBD=(const float*)d_in[3];
  const float* WLEN=(const float*)d_in[4];
  const float* BLEN=(const float*)d_in[5];
  const float* WIAT=(const float*)d_in[6];
  const float* BIAT=(const float*)d_in[7];
  const float* WFUS=(const float*)d_in[8];
  const float* BFUS=(const float*)d_in[9];
  const float* GTOK=(const float*)d_in[10];
  const float* BTOK=(const float*)d_in[11];
  const float* GN  =(const float*)d_in[12];
  const float* BNb =(const float*)d_in[13];
  const float* WH1 =(const float*)d_in[14];
  const float* BH1 =(const float*)d_in[15];
  const float* WH2 =(const float*)d_in[16];
  const float* BH2 =(const float*)d_in[17];
  const float* INW[2]={(const float*)d_in[18],(const float*)d_in[27]};
  const float* CW [2]={(const float*)d_in[19],(const float*)d_in[28]};
  const float* CB [2]={(const float*)d_in[20],(const float*)d_in[29]};
  const float* XPW[2]={(const float*)d_in[21],(const float*)d_in[30]};
  const float* DTW[2]={(const float*)d_in[22],(const float*)d_in[31]};
  const float* DTB[2]={(const float*)d_in[23],(const float*)d_in[32]};
  const float* AL [2]={(const float*)d_in[24],(const float*)d_in[33]};
  const float* DP [2]={(const float*)d_in[25],(const float*)d_in[34]};
  const float* OW [2]={(const float*)d_in[26],(const float*)d_in[35]};

  float *feat,*xz,*xc,*xd4,*dlt,*outf,*outb,*sumA,*sumS,*ent,*pool;
  u16 *fh,*fl,*yh,*yl,*iwh,*iwl,*owh,*owl;
  hipGetSymbolAddress((void**)&feat, HIP_SYMBOL(g_feat));
  hipGetSymbolAddress((void**)&xz,   HIP_SYMBOL(g_xz));
  hipGetSymbolAddress((void**)&xc,   HIP_SYMBOL(g_xc));
  hipGetSymbolAddress((void**)&xd4,  HIP_SYMBOL(g_xdbl4));
  hipGetSymbolAddress((void**)&dlt,  HIP_SYMBOL(g_dlt));
  hipGetSymbolAddress((void**)&outf, HIP_SYMBOL(g_outf));
  hipGetSymbolAddress((void**)&outb, HIP_SYMBOL(g_outb));
  hipGetSymbolAddress((void**)&sumA, HIP_SYMBOL(g_sumA));
  hipGetSymbolAddress((void**)&sumS, HIP_SYMBOL(g_sumS));
  hipGetSymbolAddress((void**)&ent,  HIP_SYMBOL(g_ent));
  hipGetSymbolAddress((void**)&pool, HIP_SYMBOL(g_pool));
  hipGetSymbolAddress((void**)&fh,   HIP_SYMBOL(g_fh));
  hipGetSymbolAddress((void**)&fl,   HIP_SYMBOL(g_fl));
  hipGetSymbolAddress((void**)&yh,   HIP_SYMBOL(g_yh));
  hipGetSymbolAddress((void**)&yl,   HIP_SYMBOL(g_yl));
  hipGetSymbolAddress((void**)&iwh,  HIP_SYMBOL(g_iwh));
  hipGetSymbolAddress((void**)&iwl,  HIP_SYMBOL(g_iwl));
  hipGetSymbolAddress((void**)&owh,  HIP_SYMBOL(g_owh));
  hipGetSymbolAddress((void**)&owl,  HIP_SYMBOL(g_owl));

  // split weights to bf16 hi/lo (both dirs per dispatch)
  const int NIW = 4*1024*DM, NOW = 4*DM*DI;
  k_cvt2<<<dim3((NIW+255)/256,2),256,0,stream>>>(INW[0],INW[1], iwh, iwl, NIW);
  k_cvt2<<<dim3((NOW+255)/256,2),256,0,stream>>>(OW[0], OW[1],  owh, owl, NOW);

  k_tokenize<<<NTOK/TT,256,0,stream>>>(X,EMBP,EMBF,EMBD,WLEN,BLEN,WIAT,BIAT,WFUS,BFUS,GTOK,BTOK,feat,fh,fl);
  for (int layer=0; layer<4; layer++){
    size_t iwoff = (size_t)layer*1024*DM;
    size_t owoff = (size_t)layer*DM*DI;
    // in_proj (MFMA): (4096x1024) = feat(4096x256) @ Wp^T
    k_gemmM<<<dim3(1024/64,4096/64,2),256,0,stream>>>(
      fh,fl,fh,fl,256,
      iwh+iwoff, iwl+iwoff, iwh+NIW+iwoff, iwl+NIW+iwoff, 256,
      xz, xz+XZS, 1024);
    // conv + silu, both dirs
    k_conv2<<<dim3(NTOK*DI/256,2),256,0,stream>>>(xz,
      CW[0]+(size_t)layer*512*4, CW[1]+(size_t)layer*512*4,
      CB[0]+(size_t)layer*512,   CB[1]+(size_t)layer*512, xc);
    // x_proj split-K -> 4 partial buffers (plain stores)
    k_gemmSK<<<dim3(4,64,2),256,0,stream>>>(
      xc, xc+XCS, 512,
      XPW[0]+(size_t)layer*48*512, XPW[1]+(size_t)layer*48*512, 512,
      xd4);
    // chunked scan trio (delta computed in A, reused in B)
    k_scanA<<<dim3(NC,NB,2),512,0,stream>>>(xc,xd4,
      AL[0]+(size_t)layer*512*16, AL[1]+(size_t)layer*512*16,
      DTW[0]+(size_t)layer*512*16, DTW[1]+(size_t)layer*512*16,
      DTB[0]+(size_t)layer*512,    DTB[1]+(size_t)layer*512,
      dlt, sumA, sumS);
    k_scanP<<<dim3(32,NB,2),256,0,stream>>>(sumA,sumS,ent);
    k_scanB<<<dim3(NC,NB,2),512,0,stream>>>(xc,xd4,xz,dlt,
      AL[0]+(size_t)layer*512*16, AL[1]+(size_t)layer*512*16,
      DP[0]+(size_t)layer*512,    DP[1]+(size_t)layer*512,
      ent, yh, yl);
    // out_proj (MFMA): (4096x256) = y(4096x512) @ Wo^T
    k_gemmM<<<dim3(256/64,4096/64,2),256,0,stream>>>(
      yh,yl, yh+XCS,yl+XCS, 512,
      owh+owoff, owl+owoff, owh+NOW+owoff, owl+NOW+owoff, 512,
      outf, outb, 256);
    k_resln<<<NTOK,256,0,stream>>>(outf,outb,feat,GN,BNb,fh,fl);
  }
  k_pool<<<dim3(8,NB),256,0,stream>>>(feat,pool);
  k_head<<<NB,256,0,stream>>>(pool,WH1,BH1,WH2,BH2,(float*)d_out);
}